// Round 6
// baseline (312.358 us; speedup 1.0000x reference)
//
#include <hip/hip_runtime.h>
#include <hip/hip_cooperative_groups.h>
namespace cg = cooperative_groups;

// Problem constants (image 128x128, TILE_SIZE=64)
#define IMG 128
#define TSZ 64
#define NTILES 4          // (128/64)^2
#define PMAX 2048
#define SELCAP 4096       // candidate cap per tile (expected ~2070)
#define NHIST 4096        // linear depth buckets (width 1/256 depth unit)
#define NCHUNK 16
#define CHUNK 128         // PMAX / NCHUNK
#define NPIX 4096         // TSZ*TSZ
#define PLANE ((size_t)NTILES * NCHUNK * NPIX)   // 262144 floats per component plane
#define NTHR 256
#define ZWORDS (NTILES*NHIST*2 + NTILES*PMAX*12) // 131072: hist+bucketFill+params
#define RUNITS 512        // render work units (tile x chunk x 8 row-groups)

typedef unsigned short u16;
typedef unsigned int uint32;
typedef unsigned long long u64;

// Linear depth bucketing: monotone in depth, uniform occupancy for uniform
// depths (float-bits>>20 concentrated ~56 buckets -> atomic serialization).
__device__ __forceinline__ uint32 dbucket(float d) {
    int b = (int)(d * 256.0f);
    return (uint32)min(max(b, 0), NHIST - 1);
}

__device__ __forceinline__ void gauss_rect(const float* means, const float* cov,
                                           int i, float& rminx, float& rminy,
                                           float& rmaxx, float& rmaxy) {
    const float4 cv = ((const float4*)cov)[i];           // a, b, c2, d
    float det = cv.x * cv.w - cv.y * cv.z;
    float mid = 0.5f * (cv.x + cv.w);
    float s = sqrtf(fmaxf(mid * mid - det, 0.1f));
    float radius = 3.0f * ceilf(sqrtf(fmaxf(mid + s, mid - s)));
    const float2 m = ((const float2*)means)[i];
    rminx = fminf(fmaxf(m.x - radius, 0.f), (float)(IMG - 1));
    rmaxx = fminf(fmaxf(m.x + radius, 0.f), (float)(IMG - 1));
    rminy = fminf(fmaxf(m.y - radius, 0.f), (float)(IMG - 1));
    rmaxy = fminf(fmaxf(m.y + radius, 0.f), (float)(IMG - 1));
}

__device__ __forceinline__ bool tile_overlap(int t, float rminx, float rminy,
                                             float rmaxx, float rmaxy) {
    float wmin = (float)((t & 1) * TSZ), hmin = (float)((t >> 1) * TSZ);
    float wmax = wmin + (float)(TSZ - 1), hmax = hmin + (float)(TSZ - 1);
    return (fminf(rmaxx, wmax) > fmaxf(rminx, wmin)) &&
           (fminf(rmaxy, hmax) > fmaxf(rminy, hmin));
}

// ============================ phase bodies (shared by fused + fallback) =====

__device__ __forceinline__ void do_zero(int gtid, int gsize, uint32* z) {
    for (int i = gtid; i < ZWORDS; i += gsize) z[i] = 0u;
}

__device__ __forceinline__ void do_preproc(int gtid, int gsize,
        const float* means, const float* cov, const float* depths,
        uint32* hist, u16* tmb, int N) {
    for (int i = gtid; i < N; i += gsize) {
        float rminx, rminy, rmaxx, rmaxy;
        gauss_rect(means, cov, i, rminx, rminy, rmaxx, rmaxy);
        uint32 b = dbucket(depths[i]);
        uint32 mask = 0;
        #pragma unroll
        for (int t = 0; t < NTILES; t++) {
            if (tile_overlap(t, rminx, rminy, rmaxx, rmaxy)) {
                mask |= (1u << t);
                atomicAdd(&hist[t * NHIST + b], 1u);
            }
        }
        tmb[i] = (u16)((mask << 12) | b);
    }
}

// tile in [0,4): threshold bucket b*, exclusive bucket prefix-sum, exact count.
__device__ __forceinline__ void do_findb(int tile, int tid,
        uint32* hh, uint32* part, uint32* sBM,
        const uint32* hist, uint32* bstar, uint32* selCount, uint32* bucketBase) {
    if (tid == 0) { sBM[0] = NHIST - 1; sBM[1] = 0; }
    const uint32* h = hist + (size_t)tile * NHIST;
    for (int j = tid; j < NHIST; j += NTHR) hh[j] = h[j];   // coalesced
    __syncthreads();
    uint32 local = 0;
    #pragma unroll
    for (int b = 0; b < 16; b++) local += hh[tid * 16 + b];
    part[tid] = local;
    __syncthreads();
    for (int off = 1; off < NTHR; off <<= 1) {
        uint32 v = part[tid];
        uint32 u = (tid >= off) ? part[tid - off] : 0u;
        __syncthreads();
        part[tid] = v + u;
        __syncthreads();
    }
    uint32 incl = part[tid], excl = incl - local;
    uint32 run = excl;
    #pragma unroll
    for (int b = 0; b < 16; b++) {
        uint32 j = (uint32)(tid * 16 + b);
        bucketBase[(size_t)tile * NHIST + j] = run;
        run += hh[j];
    }
    if (excl < PMAX && incl >= PMAX) {                    // unique crossing thread
        uint32 cum = excl;
        for (int b = 0; b < 16; b++) {
            cum += hh[tid * 16 + b];
            if (cum >= PMAX) { sBM[0] = (uint32)(tid * 16 + b); sBM[1] = cum; break; }
        }
    }
    __syncthreads();
    if (tid == 0) {
        bstar[tile] = sBM[0];
        selCount[tile] = (sBM[1] != 0) ? sBM[1] : part[NTHR - 1];
    }
}

__device__ __forceinline__ void do_compact(int gtid, int gsize,
        const u16* tmb, const float* depths, const uint32* bstar,
        const uint32* bucketBase, uint32* bucketFill, u64* sel, int N) {
    for (int i = gtid; i < N; i += gsize) {
        uint32 tm = tmb[i];
        uint32 mask = tm >> 12;
        if (!mask) continue;
        uint32 b = tm & 0xFFFu;
        u64 key = ((u64)__float_as_uint(depths[i]) << 32) | (uint32)i;
        #pragma unroll
        for (int t = 0; t < NTILES; t++) {
            if (((mask >> t) & 1u) && b <= bstar[t]) {
                uint32 pos = bucketBase[(size_t)t * NHIST + b]
                           + atomicAdd(&bucketFill[(size_t)t * NHIST + b], 1u);
                if (pos < SELCAP) sel[(size_t)t * SELCAP + pos] = key;
            }
        }
    }
}

// unit in [0,64): rank = exact sorted slot; emit render-param record.
__device__ __forceinline__ void do_rank(int unit, int tid, u64* keys,
        const u64* sel, const uint32* selCount,
        const float* means, const float* cov,
        const float* color, const float* opac, float* params) {
    const int tile = unit >> 4;
    uint32 M = selCount[tile]; if (M > SELCAP) M = SELCAP;
    uint32 Mp = (M + 7u) & ~7u;
    const u64* s = sel + (size_t)tile * SELCAP;
    for (uint32 j = tid; j < Mp; j += NTHR)
        keys[j] = (j < M) ? s[j] : ~0ULL;
    __syncthreads();
    uint32 i = (uint32)(unit & 15) * NTHR + tid;
    if (i >= M) return;
    u64 ki = keys[i];
    uint32 r = 0;
    const ulonglong2* k2 = (const ulonglong2*)keys;
    uint32 n2 = Mp >> 1;
    #pragma unroll 8
    for (uint32 j = 0; j < n2; j++) {
        ulonglong2 kk = k2[j];                            // LDS broadcast (16B)
        r += (kk.x < ki) ? 1u : 0u;
        r += (kk.y < ki) ? 1u : 0u;
    }
    if (r < PMAX) {
        uint32 idx = (uint32)(ki & 0xffffffffu);
        float a = cov[4*idx], b = cov[4*idx+1], c2 = cov[4*idx+2], d = cov[4*idx+3];
        float invdet = 1.0f / fmaxf(a * d - b * c2, 1e-6f);
        float4 p0, p1, p2;
        p0.x = means[2*idx]; p0.y = means[2*idx+1];
        p0.z = d * invdet;                 // c00
        p0.w = -(b + c2) * invdet;         // c01 + c10
        p1.x = a * invdet;                 // c11
        p1.y = opac[idx];
        p1.z = color[3*idx]; p1.w = color[3*idx+1];
        p2.x = color[3*idx+2];
        p2.y = __uint_as_float((uint32)(ki >> 32));   // depth
        p2.z = 0.f; p2.w = 0.f;
        float4* P = (float4*)(params + ((size_t)tile * PMAX + r) * 12);
        P[0] = p0; P[1] = p1; P[2] = p2;
    }
}

// unit in [0,512): 2 px/thread (rows y, y+32 share all LDS reads).
__device__ __forceinline__ void do_render(int unit, int tid, float4* gp,
        const float* params, float* partials) {
    const int tile  = unit >> 7;
    const int chunk = (unit >> 3) & 15;
    const int pseg  = unit & 7;
    const float4* src = (const float4*)(params + ((size_t)tile * PMAX + (size_t)chunk * CHUNK) * 12);
    for (int j = tid; j < CHUNK * 3; j += NTHR) gp[j] = src[j];
    __syncthreads();
    const int p0 = pseg * 256 + tid;               // rows pseg*4 .. pseg*4+3
    float px  = (float)((tile & 1) * TSZ + (p0 & 63));
    float py0 = (float)((tile >> 1) * TSZ + (p0 >> 6));
    float py1 = py0 + 32.0f;
    float T0 = 1.f, cr0 = 0.f, cg0 = 0.f, cb0 = 0.f, dp0 = 0.f, ac0 = 0.f;
    float T1 = 1.f, cr1 = 0.f, cg1 = 0.f, cb1 = 0.f, dp1 = 0.f, ac1 = 0.f;
    #pragma unroll 4
    for (int g = 0; g < CHUNK; g++) {
        float4 q0 = gp[3*g], q1 = gp[3*g+1], q2 = gp[3*g+2];
        float dx   = px - q0.x;
        float dx2c = dx * dx * q0.z;
        float dxw  = dx * q0.w;
        float dy, power, al, w;
        dy = py0 - q0.y;
        power = -0.5f * (dx2c + dy * dy * q1.x + dy * dxw);
        al = fminf(__expf(power) * q1.y, 0.99f);
        w = al * T0;
        cr0 += w * q1.z; cg0 += w * q1.w; cb0 += w * q2.x;
        dp0 += w * q2.y; ac0 += w;
        T0 *= (1.f - al);
        dy = py1 - q0.y;
        power = -0.5f * (dx2c + dy * dy * q1.x + dy * dxw);
        al = fminf(__expf(power) * q1.y, 0.99f);
        w = al * T1;
        cr1 += w * q1.z; cg1 += w * q1.w; cb1 += w * q2.x;
        dp1 += w * q2.y; ac1 += w;
        T1 *= (1.f - al);
    }
    size_t base0 = ((size_t)tile * NCHUNK + chunk) * NPIX + (size_t)p0;
    size_t base1 = base0 + 2048;                   // row +32
    partials[0*PLANE + base0] = T0;  partials[0*PLANE + base1] = T1;
    partials[1*PLANE + base0] = cr0; partials[1*PLANE + base1] = cr1;
    partials[2*PLANE + base0] = cg0; partials[2*PLANE + base1] = cg1;
    partials[3*PLANE + base0] = cb0; partials[3*PLANE + base1] = cb1;
    partials[4*PLANE + base0] = dp0; partials[4*PLANE + base1] = dp1;
    partials[5*PLANE + base0] = ac0; partials[5*PLANE + base1] = ac1;
}

// unit in [0,64): fold chunks via (T1*T2, S1 + T1*S2).
__device__ __forceinline__ void do_combine(int unit, int tid,
        const float* partials, float* out) {
    int q = unit * NTHR + tid;                      // 0..16383
    int tile = q >> 12, p = q & (NPIX - 1);
    float T = 1.f, cr = 0.f, cg = 0.f, cb = 0.f, dep = 0.f, acc = 0.f;
    #pragma unroll
    for (int c = 0; c < NCHUNK; c++) {
        size_t base = ((size_t)tile * NCHUNK + c) * NPIX + (size_t)p;
        float Tk = partials[0*PLANE + base];
        cr  += T * partials[1*PLANE + base];
        cg  += T * partials[2*PLANE + base];
        cb  += T * partials[3*PLANE + base];
        dep += T * partials[4*PLANE + base];
        acc += T * partials[5*PLANE + base];
        T *= Tk;
    }
    int gx = (tile & 1) * TSZ + (p & 63);
    int gy = (tile >> 1) * TSZ + (p >> 6);
    int pix = gy * IMG + gx;
    float wb = 1.f - acc;                           // WHITE_BKGD
    out[3*pix+0] = cr + wb;
    out[3*pix+1] = cg + wb;
    out[3*pix+2] = cb + wb;
    out[IMG*IMG*3 + pix] = dep;
    out[IMG*IMG*4 + pix] = acc;
}

// ============================ fused cooperative kernel ======================
// All phases are grid-stride -> correct for ANY co-resident grid size.
__global__ __launch_bounds__(NTHR, 2) void fused(
        const float* __restrict__ means, const float* __restrict__ cov,
        const float* __restrict__ color, const float* __restrict__ opac,
        const float* __restrict__ depths, int N,
        uint32* __restrict__ hist, uint32* __restrict__ bucketFill,
        float* __restrict__ params, uint32* __restrict__ bstar,
        uint32* __restrict__ selCount, uint32* __restrict__ bucketBase,
        u16* __restrict__ tmb, u64* __restrict__ sel,
        float* __restrict__ partials, float* __restrict__ out) {
    cg::grid_group grid = cg::this_grid();
    const int blk = blockIdx.x, tid = threadIdx.x, gdim = gridDim.x;
    const int gtid = blk * NTHR + tid, gsize = gdim * NTHR;

    __shared__ __align__(16) char shraw[SELCAP * 8];   // 32 KB, phase-aliased
    __shared__ uint32 part[NTHR];
    __shared__ uint32 sBM[2];

    do_zero(gtid, gsize, hist);
    grid.sync();
    do_preproc(gtid, gsize, means, cov, depths, hist, tmb, N);
    grid.sync();
    for (int u = blk; u < NTILES; u += gdim) {
        do_findb(u, tid, (uint32*)shraw, part, sBM, hist, bstar, selCount, bucketBase);
        __syncthreads();
    }
    grid.sync();
    do_compact(gtid, gsize, tmb, depths, bstar, bucketBase, bucketFill, sel, N);
    grid.sync();
    for (int u = blk; u < 64; u += gdim) {
        __syncthreads();
        do_rank(u, tid, (u64*)shraw, sel, selCount, means, cov, color, opac, params);
        __syncthreads();
    }
    grid.sync();
    for (int u = blk; u < RUNITS; u += gdim) {
        __syncthreads();
        do_render(u, tid, (float4*)shraw, params, partials);
    }
    grid.sync();
    for (int u = blk; u < 64; u += gdim)
        do_combine(u, tid, partials, out);
}

// ============================ standalone fallback kernels ===================
__global__ __launch_bounds__(NTHR) void k_zero(uint32* z) {
    do_zero(blockIdx.x * NTHR + threadIdx.x, gridDim.x * NTHR, z);
}
__global__ __launch_bounds__(NTHR) void k_preproc(const float* means, const float* cov,
        const float* depths, uint32* hist, u16* tmb, int N) {
    do_preproc(blockIdx.x * NTHR + threadIdx.x, gridDim.x * NTHR,
               means, cov, depths, hist, tmb, N);
}
__global__ __launch_bounds__(NTHR) void k_findb(const uint32* hist, uint32* bstar,
        uint32* selCount, uint32* bucketBase) {
    __shared__ uint32 hh[NHIST];
    __shared__ uint32 part[NTHR];
    __shared__ uint32 sBM[2];
    do_findb(blockIdx.x, threadIdx.x, hh, part, sBM, hist, bstar, selCount, bucketBase);
}
__global__ __launch_bounds__(NTHR) void k_compact(const u16* tmb, const float* depths,
        const uint32* bstar, const uint32* bucketBase, uint32* bucketFill,
        u64* sel, int N) {
    do_compact(blockIdx.x * NTHR + threadIdx.x, gridDim.x * NTHR,
               tmb, depths, bstar, bucketBase, bucketFill, sel, N);
}
__global__ __launch_bounds__(NTHR) void k_rank(const u64* sel, const uint32* selCount,
        const float* means, const float* cov, const float* color,
        const float* opac, float* params) {
    __shared__ __align__(16) u64 keys[SELCAP];
    do_rank(blockIdx.x, threadIdx.x, keys, sel, selCount, means, cov, color, opac, params);
}
__global__ __launch_bounds__(NTHR) void k_render(const float* params, float* partials) {
    __shared__ __align__(16) float4 gp[CHUNK * 3];
    do_render(blockIdx.x, threadIdx.x, gp, params, partials);
}
__global__ __launch_bounds__(NTHR) void k_combine(const float* partials, float* out) {
    do_combine(blockIdx.x, threadIdx.x, partials, out);
}

// ------------------------------------------------------------------ launch --
extern "C" void kernel_launch(void* const* d_in, const int* in_sizes, int n_in,
                              void* d_out, int out_size, void* d_ws, size_t ws_size,
                              hipStream_t stream) {
    const float* means  = (const float*)d_in[0];
    const float* cov    = (const float*)d_in[1];
    const float* color  = (const float*)d_in[2];
    const float* opac   = (const float*)d_in[3];
    const float* depths = (const float*)d_in[4];
    int N = in_sizes[4];

    char* ws = (char*)d_ws;
    size_t off = 0;
    // hist, bucketFill, params contiguous (zeroed together in phase 0)
    uint32* hist       = (uint32*)(ws + off); off += (size_t)NTILES * NHIST * 4;   // 64 KB
    uint32* bucketFill = (uint32*)(ws + off); off += (size_t)NTILES * NHIST * 4;   // 64 KB
    float*  params     = (float*)(ws + off);  off += (size_t)NTILES * PMAX * 12 * 4; // 384 KB
    uint32* bstar      = (uint32*)(ws + off); off += 256;
    uint32* selCount   = (uint32*)(ws + off); off += 256;
    uint32* bucketBase = (uint32*)(ws + off); off += (size_t)NTILES * NHIST * 4;   // 64 KB
    u16*    tmb        = (u16*)(ws + off);    off += ((size_t)N * 2 + 255) & ~255ull;
    u64*    sel        = (u64*)(ws + off);    off += (size_t)NTILES * SELCAP * 8;  // 128 KB
    float*  partials   = (float*)(ws + off);  off += 6 * PLANE * 4;                // 6 MB
    float*  out        = (float*)d_out;

    // Query a provably co-resident grid (host-side only; kernel_launch runs at
    // capture time, so these API calls cost nothing at replay).
    int dev = 0;
    (void)hipGetDevice(&dev);
    int numCU = 0;
    (void)hipDeviceGetAttribute(&numCU, hipDeviceAttributeMultiprocessorCount, dev);
    int nb = 0;
    hipError_t eo = hipOccupancyMaxActiveBlocksPerMultiprocessor(
        &nb, (const void*)fused, NTHR, 0);
    int grid = RUNITS;
    if (eo == hipSuccess && nb > 0 && numCU > 0) {
        long cap = (long)nb * (long)numCU;
        if (cap < grid) grid = (int)cap;
    }
    if (grid < 1) grid = 1;

    void* args[] = { (void*)&means, (void*)&cov, (void*)&color, (void*)&opac,
                     (void*)&depths, (void*)&N, (void*)&hist, (void*)&bucketFill,
                     (void*)&params, (void*)&bstar, (void*)&selCount,
                     (void*)&bucketBase, (void*)&tmb, (void*)&sel,
                     (void*)&partials, (void*)&out };
    hipError_t e = hipLaunchCooperativeKernel((const void*)fused, dim3(grid),
                                              dim3(NTHR), args, 0, stream);
    if (e != hipSuccess) {
        (void)hipGetLastError();   // clear sticky error; use proven 7-kernel path
        k_zero<<<(ZWORDS + NTHR - 1) / NTHR, NTHR, 0, stream>>>(hist);
        k_preproc<<<(N + NTHR - 1) / NTHR, NTHR, 0, stream>>>(means, cov, depths,
                                                              hist, tmb, N);
        k_findb<<<NTILES, NTHR, 0, stream>>>(hist, bstar, selCount, bucketBase);
        k_compact<<<(N + NTHR - 1) / NTHR, NTHR, 0, stream>>>(tmb, depths, bstar,
                                                              bucketBase, bucketFill,
                                                              sel, N);
        k_rank<<<64, NTHR, 0, stream>>>(sel, selCount, means, cov, color, opac, params);
        k_render<<<RUNITS, NTHR, 0, stream>>>(params, partials);
        k_combine<<<64, NTHR, 0, stream>>>(partials, out);
    }
}